// Round 17
// baseline (486.808 us; speedup 1.0000x reference)
//
#include <hip/hip_runtime.h>
#include <hip/hip_bf16.h>

#define HH 128
#define NN 1024
#define KNBR 30
#define NV 21
#define LEPS 1e-5f

typedef unsigned short ushort_t;
typedef __attribute__((ext_vector_type(8))) short short8;
typedef __attribute__((ext_vector_type(4))) short shortv4;
typedef __attribute__((ext_vector_type(4))) float f32x4;

__device__ __forceinline__ ushort_t f2us(float f) {
  __hip_bfloat16 h = __float2bfloat16(f);
  return __builtin_bit_cast(unsigned short, h);
}
__device__ __forceinline__ float us2f(ushort_t u) {
  __hip_bfloat16 h = __builtin_bit_cast(__hip_bfloat16, u);
  return __bfloat162float(h);
}

// async global->LDS 16B copy (lane l writes lds + l*16)
__device__ __forceinline__ void gl_lds16(const ushort_t* g, ushort_t* l) {
  __builtin_amdgcn_global_load_lds(
      (const __attribute__((address_space(1))) void*)g,
      (__attribute__((address_space(3))) void*)l, 16, 0, 0);
}

// XOR-swizzled LDS helpers (row-major, rowB bytes/row, swizzle within 128B)
__device__ __forceinline__ void sw_store8(ushort_t* base, int row, int rowB, int colByte, short8 v) {
  int byte = row * rowB + colByte;
  byte ^= (row & 7) << 4;
  *(short8*)((char*)base + byte) = v;
}
__device__ __forceinline__ short8 sw_load8(const ushort_t* base, int row, int rowB, int colByte) {
  int byte = row * rowB + colByte;
  byte ^= (row & 7) << 4;
  return *(const short8*)((const char*)base + byte);
}
__device__ __forceinline__ void sw_store1(ushort_t* base, int row, int rowB, int col, ushort_t v) {
  int byte = row * rowB + col * 2;
  byte ^= (row & 7) << 4;
  *(ushort_t*)((char*)base + byte) = v;
}

// ---------------- merged weight prep: up to 40 tensors in one launch ----------------
// frag idx: ((k>>5)*NT + (c>>4))*512 + (((k&31)>>3)*16 + (c&15))*8 + (k&7)
struct PrepTab {
  const float* src[40];
  unsigned dstOff[40];
  int blk0[40];     // starting block of each tensor (each block = 256 elems)
  int nshift[40];
};

__global__ __launch_bounds__(256) void k_prep_all(PrepTab tab, ushort_t* __restrict__ dst,
                                                  float* __restrict__ zbuf) {
  const int bid = blockIdx.x;
  if (bid == 0) zbuf[threadIdx.x] = 0.f;  // 1KB zero region for gather zero-fill
  int ti = 0;
#pragma unroll 1
  for (int i = 1; i < 40; ++i)
    if (bid >= tab.blk0[i]) ti = i;
  const int nshift = tab.nshift[ti];
  const int e = (bid - tab.blk0[ti]) * 256 + threadIdx.x;
  const int k = e >> nshift;
  const int c = e & ((1 << nshift) - 1);
  const int NT = 1 << (nshift - 4);
  const int idx = ((k >> 5) * NT + (c >> 4)) * 512 + (((k & 31) >> 3) * 16 + (c & 15)) * 8 + (k & 7);
  dst[tab.dstOff[ti] + idx] = f2us(tab.src[ti][e]);
}

// ---------------- 64x128x128 MFMA GEMM over row tiles (f32 A), bf16 out ----------------
__global__ __launch_bounds__(256) void k_gemm64(
    const float* __restrict__ A, const ushort_t* __restrict__ Wf,
    const float* __restrict__ bias, ushort_t* __restrict__ out)
{
  const int t = threadIdx.x, wid = t >> 6, lane = t & 63;
  const int wm = wid >> 1, wn = wid & 1;
  const size_t row0 = (size_t)blockIdx.x * 64;
  __shared__ alignas(16) ushort_t Xs[64 * 128];  // 16KB, rowB=256

  {
    const int row = t >> 2, q = t & 3;
    const float4* p = (const float4*)(A + (row0 + row) * HH + q * 32);
#pragma unroll
    for (int i = 0; i < 4; ++i) {
      short8 wv;
#pragma unroll
      for (int jj = 0; jj < 2; ++jj) {
        const float4 x = p[i * 2 + jj];
        wv[jj * 4 + 0] = (short)f2us(x.x);
        wv[jj * 4 + 1] = (short)f2us(x.y);
        wv[jj * 4 + 2] = (short)f2us(x.z);
        wv[jj * 4 + 3] = (short)f2us(x.w);
      }
      sw_store8(Xs, row, 256, q * 64 + i * 16, wv);
    }
  }
  __syncthreads();

  f32x4 acc[2][4];
#pragma unroll
  for (int ni = 0; ni < 4; ++ni) {
    const float bv = bias[wn * 64 + ni * 16 + (lane & 15)];
#pragma unroll
    for (int mi = 0; mi < 2; ++mi) acc[mi][ni] = {bv, bv, bv, bv};
  }
#pragma unroll
  for (int kb = 0; kb < 4; ++kb) {
    short8 Af[2], Bf[4];
#pragma unroll
    for (int mi = 0; mi < 2; ++mi)
      Af[mi] = sw_load8(Xs, wm * 32 + mi * 16 + (lane & 15), 256, kb * 64 + (lane >> 4) * 16);
#pragma unroll
    for (int ni = 0; ni < 4; ++ni)
      Bf[ni] = *(const short8*)&Wf[(((size_t)kb * 8 + wn * 4 + ni) * 64 + lane) * 8];
#pragma unroll
    for (int mi = 0; mi < 2; ++mi)
#pragma unroll
      for (int ni = 0; ni < 4; ++ni)
        acc[mi][ni] = __builtin_amdgcn_mfma_f32_16x16x32_bf16(Af[mi], Bf[ni], acc[mi][ni], 0, 0, 0);
  }

  __syncthreads();
#pragma unroll
  for (int mi = 0; mi < 2; ++mi)
#pragma unroll
    for (int ni = 0; ni < 4; ++ni)
#pragma unroll
      for (int q = 0; q < 4; ++q) {
        const int row = wm * 32 + mi * 16 + (lane >> 4) * 4 + q;
        const int col = wn * 64 + ni * 16 + (lane & 15);
        sw_store1(Xs, row, 256, col, f2us(acc[mi][ni][q]));
      }
  __syncthreads();
  {
    const int row = t >> 2, q = t & 3;
    ushort_t* o = out + (row0 + row) * HH + q * 32;
#pragma unroll
    for (int i = 0; i < 4; ++i)
      *(short8*)(o + i * 8) = sw_load8(Xs, row, 256, q * 64 + i * 16);
  }
}

// ---------------- same but bf16 A (for initial selfb = hV @ W1self + b1) ----------------
__global__ __launch_bounds__(256) void k_gemm64b(
    const ushort_t* __restrict__ A, const ushort_t* __restrict__ Wf,
    const float* __restrict__ bias, ushort_t* __restrict__ out)
{
  const int t = threadIdx.x, wid = t >> 6, lane = t & 63;
  const int wm = wid >> 1, wn = wid & 1;
  const size_t row0 = (size_t)blockIdx.x * 64;
  __shared__ alignas(16) ushort_t Xs[64 * 128];

  {
    const int row = t >> 2, q = t & 3;
    const short8* p = (const short8*)(A + (row0 + row) * HH + q * 32);
#pragma unroll
    for (int i = 0; i < 4; ++i)
      sw_store8(Xs, row, 256, q * 64 + i * 16, p[i]);
  }
  __syncthreads();

  f32x4 acc[2][4];
#pragma unroll
  for (int ni = 0; ni < 4; ++ni) {
    const float bv = bias[wn * 64 + ni * 16 + (lane & 15)];
#pragma unroll
    for (int mi = 0; mi < 2; ++mi) acc[mi][ni] = {bv, bv, bv, bv};
  }
#pragma unroll
  for (int kb = 0; kb < 4; ++kb) {
    short8 Af[2], Bf[4];
#pragma unroll
    for (int mi = 0; mi < 2; ++mi)
      Af[mi] = sw_load8(Xs, wm * 32 + mi * 16 + (lane & 15), 256, kb * 64 + (lane >> 4) * 16);
#pragma unroll
    for (int ni = 0; ni < 4; ++ni)
      Bf[ni] = *(const short8*)&Wf[(((size_t)kb * 8 + wn * 4 + ni) * 64 + lane) * 8];
#pragma unroll
    for (int mi = 0; mi < 2; ++mi)
#pragma unroll
      for (int ni = 0; ni < 4; ++ni)
        acc[mi][ni] = __builtin_amdgcn_mfma_f32_16x16x32_bf16(Af[mi], Bf[ni], acc[mi][ni], 0, 0, 0);
  }

  __syncthreads();
#pragma unroll
  for (int mi = 0; mi < 2; ++mi)
#pragma unroll
    for (int ni = 0; ni < 4; ++ni)
#pragma unroll
      for (int q = 0; q < 4; ++q) {
        const int row = wm * 32 + mi * 16 + (lane >> 4) * 4 + q;
        const int col = wn * 64 + ni * 16 + (lane & 15);
        sw_store1(Xs, row, 256, col, f2us(acc[mi][ni][q]));
      }
  __syncthreads();
  {
    const int row = t >> 2, q = t & 3;
    ushort_t* o = out + (row0 + row) * HH + q * 32;
#pragma unroll
    for (int i = 0; i < 4; ++i)
      *(short8*)(o + i * 8) = sw_load8(Xs, row, 256, q * 64 + i * 16);
  }
}

// ---------------- h_S = Ws_emb[S] (bf16), vectorized gather ----------------
__global__ __launch_bounds__(256) void k_hs(
    const int* __restrict__ S, const float* __restrict__ Wse, ushort_t* __restrict__ hS)
{
  const int e = blockIdx.x * 256 + threadIdx.x;
  const int r = e >> 5, cq = e & 31;
  const float4 x = *(const float4*)(Wse + (size_t)S[r] * HH + cq * 4);
  shortv4 v;
  v[0] = (short)f2us(x.x); v[1] = (short)f2us(x.y);
  v[2] = (short)f2us(x.z); v[3] = (short)f2us(x.w);
  *(shortv4*)(hS + (size_t)r * HH + cq * 4) = v;
}

// ---------------- MFMA message kernel: global_load_lds staging ----------------
template <int DEC>
__global__ __launch_bounds__(256) void k_msg(
    const ushort_t* __restrict__ hV_in, const ushort_t* __restrict__ hV_enc,
    const ushort_t* __restrict__ hS, const ushort_t* __restrict__ hE,
    const ushort_t* __restrict__ W1f, const ushort_t* __restrict__ W2f,
    const ushort_t* __restrict__ W3f, const ushort_t* __restrict__ selfb,
    const ushort_t* __restrict__ zbuf,
    const float* __restrict__ b2, const float* __restrict__ b3,
    const float* __restrict__ g1, const float* __restrict__ bt1,
    const int* __restrict__ E_idx, const float* __restrict__ mask,
    ushort_t* __restrict__ h1out)
{
  constexpr int INFR = DEC ? 3 * HH : 2 * HH;   // X width excluding self block
  constexpr int SLABS = INFR / 64;              // 6 (dec) / 4 (enc)
  const int t = threadIdx.x;
  const int wid = t >> 6, lane = t & 63;
  const int wm = wid >> 1, wn = wid & 1;
  const int node0 = blockIdx.x * 4;
  const int bb = node0 >> 10;
  const int np0 = node0 & (NN - 1);

  __shared__ alignas(16) ushort_t U[128 * 128];  // 32KB union: {Xa|Xb} | Ys | dhs
  __shared__ int s_nb[128];
  __shared__ float s_watt[128];
  __shared__ signed char s_ar[128];
  __shared__ float sself[4][HH];                 // 2KB: per-node self term (f32)
  ushort_t* Xa = U;
  ushort_t* Xb = U + 128 * 64;
  ushort_t* Ys = U;
  float* dhs = (float*)U;

  if (t < 128) {
    const int g = t >> 5, e = t & 31;
    const int r = node0 + g;
    int nb = 0, arI = 0;
    float watt = 0.f;
    if (e < KNBR) {
      nb = E_idx[(size_t)r * KNBR + e];
      if (DEC) {
        arI = (nb < np0 + g) ? 1 : 0;
        watt = 1.f;
      } else {
        watt = mask[r] * mask[bb * NN + nb];
      }
    }
    s_nb[t] = nb; s_watt[t] = watt; s_ar[t] = (signed char)arI;
  }
  // stage selfb for the block's 4 nodes (512 elems, 2 per thread)
  {
    const int i0 = t, i1 = t + 256;
    sself[i0 >> 7][i0 & 127] = us2f(selfb[(size_t)(node0 + (i0 >> 7)) * HH + (i0 & 127)]);
    sself[i1 >> 7][i1 & 127] = us2f(selfb[(size_t)(node0 + (i1 >> 7)) * HH + (i1 & 127)]);
  }
  __syncthreads();

  // ---- per-j pre-swizzled global base pointers ----
  const int elemOff = (((lane & 7) ^ (lane >> 3)) << 3);
  const ushort_t* pj0[4];
  const ushort_t* pj1[4];
  const ushort_t* pj2[4];
#pragma unroll
  for (int j = 0; j < 4; ++j) {
    const int se = j * 8 + (lane >> 3);
    const bool valid = (se < KNBR);
    const int nb = s_nb[wid * 32 + se];
    const bool ar = (bool)s_ar[wid * 32 + se];
    pj0[j] = valid ? (hE + ((size_t)(node0 + wid) * KNBR + se) * HH + elemOff) : zbuf;
    if (DEC) {
      pj1[j] = (valid && ar) ? (hS + (size_t)(bb * NN + nb) * HH + elemOff) : zbuf;
      pj2[j] = valid ? ((ar ? hV_in : hV_enc) + (size_t)(bb * NN + nb) * HH + elemOff) : zbuf;
    } else {
      pj1[j] = valid ? (hV_in + (size_t)(bb * NN + nb) * HH + elemOff) : zbuf;
      pj2[j] = zbuf;
    }
  }

  auto stage_async = [&](int s, ushort_t* buf) {
#pragma unroll
    for (int j = 0; j < 4; ++j) {
      const ushort_t* base = (s < 2) ? pj0[j] : ((!DEC || s < 4) ? pj1[j] : pj2[j]);
      gl_lds16(base + (s & 1) * 64, buf + wid * 2048 + j * 512);
    }
  };

  // acc init from self term (same value for all 4 q-rows of a node)
  f32x4 acc[4][4];
#pragma unroll
  for (int mi = 0; mi < 4; ++mi) {
    const int g = wm * 2 + (mi >> 1);
#pragma unroll
    for (int ni = 0; ni < 4; ++ni) {
      const float v = sself[g][wn * 64 + ni * 16 + (lane & 15)];
      acc[mi][ni] = {v, v, v, v};
    }
  }

  // ---- GEMM1 (K = INFR): async double-buffered slabs, one barrier per slab ----
  stage_async(0, Xa);
  __syncthreads();  // drains vmcnt -> Xa ready

  for (int s = 0; s < SLABS; ++s) {
    ushort_t* cur = (s & 1) ? Xb : Xa;
    ushort_t* nxt = (s & 1) ? Xa : Xb;
    if (s + 1 < SLABS) stage_async(s + 1, nxt);  // async, lands before next barrier
#pragma unroll
    for (int kb = 0; kb < 2; ++kb) {
      const int kbg = s * 2 + kb;
      short8 A[4], Bf[4];
#pragma unroll
      for (int mi = 0; mi < 4; ++mi)
        A[mi] = sw_load8(cur, wm * 64 + mi * 16 + (lane & 15), 128, kb * 64 + (lane >> 4) * 16);
#pragma unroll
      for (int ni = 0; ni < 4; ++ni)
        Bf[ni] = *(const short8*)&W1f[(((size_t)kbg * 8 + wn * 4 + ni) * 64 + lane) * 8];
#pragma unroll
      for (int mi = 0; mi < 4; ++mi)
#pragma unroll
        for (int ni = 0; ni < 4; ++ni)
          acc[mi][ni] = __builtin_amdgcn_mfma_f32_16x16x32_bf16(A[mi], Bf[ni], acc[mi][ni], 0, 0, 0);
    }
    __syncthreads();
  }

  // write Y1 = relu(.) into union (X buffers dead after final barrier)
#pragma unroll
  for (int mi = 0; mi < 4; ++mi)
#pragma unroll
    for (int ni = 0; ni < 4; ++ni)
#pragma unroll
      for (int q = 0; q < 4; ++q) {
        const int row = wm * 64 + mi * 16 + (lane >> 4) * 4 + q;
        const int col = wn * 64 + ni * 16 + (lane & 15);
        sw_store1(Ys, row, 256, col, f2us(fmaxf(acc[mi][ni][q], 0.f)));
      }
  __syncthreads();

  // ---- GEMM2 ----
#pragma unroll
  for (int ni = 0; ni < 4; ++ni) {
    const float bv = b2[wn * 64 + ni * 16 + (lane & 15)];
#pragma unroll
    for (int mi = 0; mi < 4; ++mi) acc[mi][ni] = {bv, bv, bv, bv};
  }
#pragma unroll
  for (int kb = 0; kb < 4; ++kb) {
    short8 A[4], Bf[4];
#pragma unroll
    for (int mi = 0; mi < 4; ++mi)
      A[mi] = sw_load8(Ys, wm * 64 + mi * 16 + (lane & 15), 256, kb * 64 + (lane >> 4) * 16);
#pragma unroll
    for (int ni = 0; ni < 4; ++ni)
      Bf[ni] = *(const short8*)&W2f[(((size_t)kb * 8 + wn * 4 + ni) * 64 + lane) * 8];
#pragma unroll
    for (int mi = 0; mi < 4; ++mi)
#pragma unroll
      for (int ni = 0; ni < 4; ++ni)
        acc[mi][ni] = __builtin_amdgcn_mfma_f32_16x16x32_bf16(A[mi], Bf[ni], acc[mi][ni], 0, 0, 0);
  }
  __syncthreads();
#pragma unroll
  for (int mi = 0; mi < 4; ++mi)
#pragma unroll
    for (int ni = 0; ni < 4; ++ni)
#pragma unroll
      for (int q = 0; q < 4; ++q) {
        const int row = wm * 64 + mi * 16 + (lane >> 4) * 4 + q;
        const int col = wn * 64 + ni * 16 + (lane & 15);
        sw_store1(Ys, row, 256, col, f2us(fmaxf(acc[mi][ni][q], 0.f)));
      }
  __syncthreads();

  // ---- GEMM3 ----
#pragma unroll
  for (int ni = 0; ni < 4; ++ni) {
    const float bv = b3[wn * 64 + ni * 16 + (lane & 15)];
#pragma unroll
    for (int mi = 0; mi < 4; ++mi) acc[mi][ni] = {bv, bv, bv, bv};
  }
#pragma unroll
  for (int kb = 0; kb < 4; ++kb) {
    short8 A[4], Bf[4];
#pragma unroll
    for (int mi = 0; mi < 4; ++mi)
      A[mi] = sw_load8(Ys, wm * 64 + mi * 16 + (lane & 15), 256, kb * 64 + (lane >> 4) * 16);
#pragma unroll
    for (int ni = 0; ni < 4; ++ni)
      Bf[ni] = *(const short8*)&W3f[(((size_t)kb * 8 + wn * 4 + ni) * 64 + lane) * 8];
#pragma unroll
    for (int mi = 0; mi < 4; ++mi)
#pragma unroll
      for (int ni = 0; ni < 4; ++ni)
        acc[mi][ni] = __builtin_amdgcn_mfma_f32_16x16x32_bf16(A[mi], Bf[ni], acc[mi][ni], 0, 0, 0);
  }
  __syncthreads();  // Ys dead; dhs overlay becomes safe

  // ---- masked sum over edge rows -> dh ----
  float wrow[4][4];
#pragma unroll
  for (int mi = 0; mi < 4; ++mi)
#pragma unroll
    for (int q = 0; q < 4; ++q)
      wrow[mi][q] = s_watt[wm * 64 + mi * 16 + (lane >> 4) * 4 + q];
#pragma unroll
  for (int ni = 0; ni < 4; ++ni) {
    float p0 = 0.f, p1 = 0.f;
#pragma unroll
    for (int q = 0; q < 4; ++q) {
      p0 += wrow[0][q] * acc[0][ni][q] + wrow[1][q] * acc[1][ni][q];
      p1 += wrow[2][q] * acc[2][ni][q] + wrow[3][q] * acc[3][ni][q];
    }
    p0 += __shfl_xor(p0, 16, 64); p0 += __shfl_xor(p0, 32, 64);
    p1 += __shfl_xor(p1, 16, 64); p1 += __shfl_xor(p1, 32, 64);
    if (lane < 16) {
      dhs[(wm * 2 + 0) * HH + wn * 64 + ni * 16 + lane] = p0;
      dhs[(wm * 2 + 1) * HH + wn * 64 + ni * 16 + lane] = p1;
    }
  }
  __syncthreads();

  // ---- LN1: wave wid handles node wid ----
  {
    const int r = node0 + wid;
    const float x0 = us2f(hV_in[(size_t)r * HH + lane]) + dhs[wid * HH + lane] * (1.f / 30.f);
    const float x1 = us2f(hV_in[(size_t)r * HH + lane + 64]) + dhs[wid * HH + lane + 64] * (1.f / 30.f);
    float sm2 = x0 + x1;
#pragma unroll
    for (int m = 32; m >= 1; m >>= 1) sm2 += __shfl_xor(sm2, m, 64);
    const float mu = sm2 * (1.f / HH);
    const float d0 = x0 - mu, d1 = x1 - mu;
    float vv = d0 * d0 + d1 * d1;
#pragma unroll
    for (int m = 32; m >= 1; m >>= 1) vv += __shfl_xor(vv, m, 64);
    const float rs = rsqrtf(vv * (1.f / HH) + LEPS);
    h1out[(size_t)r * HH + lane] = f2us(g1[lane] * d0 * rs + bt1[lane]);
    h1out[(size_t)r * HH + lane + 64] = f2us(g1[lane + 64] * d1 * rs + bt1[lane + 64]);
  }
}

// ---------------- FF kernel: 32 rows/block; bf16 hV out; fused next-layer selfb;
// optional fused logits + log_softmax (final layer) ----------------
__global__ __launch_bounds__(256) void k_ff(
    const ushort_t* __restrict__ h1, const ushort_t* __restrict__ Winf,
    const ushort_t* __restrict__ Wfff,
    const float* __restrict__ bin, const float* __restrict__ bff,
    const float* __restrict__ g2, const float* __restrict__ bt2,
    const float* __restrict__ mask, ushort_t* __restrict__ hV_out,
    const ushort_t* __restrict__ Wn1f, const float* __restrict__ bn1,
    ushort_t* __restrict__ selfb_out,
    const float* __restrict__ Wout, const float* __restrict__ bout,
    float* __restrict__ lout)
{
  const int t = threadIdx.x, wid = t >> 6, lane = t & 63;
  const int row0 = blockIdx.x * 32;
  __shared__ alignas(16) ushort_t As[32 * 128];
  __shared__ alignas(16) ushort_t Us[32 * 512];

  {
    const int row = t >> 3, oct = t & 7;
    const short8* p = (const short8*)(h1 + (size_t)(row0 + row) * HH + oct * 16);
    sw_store8(As, row, 256, oct * 32, p[0]);
    sw_store8(As, row, 256, oct * 32 + 16, p[1]);
  }
  __syncthreads();

  f32x4 ua[2][8];
#pragma unroll
  for (int ni = 0; ni < 8; ++ni) {
    const float bv = bin[wid * 128 + ni * 16 + (lane & 15)];
#pragma unroll
    for (int mi = 0; mi < 2; ++mi) ua[mi][ni] = {bv, bv, bv, bv};
  }
#pragma unroll
  for (int kb = 0; kb < 4; ++kb) {
    short8 A[2], Bf[8];
#pragma unroll
    for (int mi = 0; mi < 2; ++mi)
      A[mi] = sw_load8(As, mi * 16 + (lane & 15), 256, kb * 64 + (lane >> 4) * 16);
#pragma unroll
    for (int ni = 0; ni < 8; ++ni)
      Bf[ni] = *(const short8*)&Winf[(((size_t)kb * 32 + wid * 8 + ni) * 64 + lane) * 8];
#pragma unroll
    for (int mi = 0; mi < 2; ++mi)
#pragma unroll
      for (int ni = 0; ni < 8; ++ni)
        ua[mi][ni] = __builtin_amdgcn_mfma_f32_16x16x32_bf16(A[mi], Bf[ni], ua[mi][ni], 0, 0, 0);
  }
#pragma unroll
  for (int mi = 0; mi < 2; ++mi)
#pragma unroll
    for (int ni = 0; ni < 8; ++ni)
#pragma unroll
      for (int q = 0; q < 4; ++q) {
        const int row = mi * 16 + (lane >> 4) * 4 + q;
        const int col = wid * 128 + ni * 16 + (lane & 15);
        sw_store1(Us, row, 1024, col, f2us(fmaxf(ua[mi][ni][q], 0.f)));
      }
  __syncthreads();

  f32x4 fa[2][2];
#pragma unroll
  for (int ni = 0; ni < 2; ++ni) {
    const float bv = bff[wid * 32 + ni * 16 + (lane & 15)];
#pragma unroll
    for (int mi = 0; mi < 2; ++mi) fa[mi][ni] = {bv, bv, bv, bv};
  }
#pragma unroll
  for (int kb = 0; kb < 16; ++kb) {
    short8 A[2], Bf[2];
#pragma unroll
    for (int mi = 0; mi < 2; ++mi)
      A[mi] = sw_load8(Us, mi * 16 + (lane & 15), 1024, kb * 64 + (lane >> 4) * 16);
#pragma unroll
    for (int ni = 0; ni < 2; ++ni)
      Bf[ni] = *(const short8*)&Wfff[(((size_t)kb * 8 + wid * 2 + ni) * 64 + lane) * 8];
#pragma unroll
    for (int mi = 0; mi < 2; ++mi)
#pragma unroll
      for (int ni = 0; ni < 2; ++ni)
        fa[mi][ni] = __builtin_amdgcn_mfma_f32_16x16x32_bf16(A[mi], Bf[ni], fa[mi][ni], 0, 0, 0);
  }
  __syncthreads();

  float* h2 = (float*)Us;
#pragma unroll
  for (int mi = 0; mi < 2; ++mi)
#pragma unroll
    for (int ni = 0; ni < 2; ++ni)
#pragma unroll
      for (int q = 0; q < 4; ++q) {
        const int row = mi * 16 + (lane >> 4) * 4 + q;
        const int col = wid * 32 + ni * 16 + (lane & 15);
        h2[row * HH + col] = us2f(h1[(size_t)(row0 + row) * HH + col]) + fa[mi][ni][q];
      }
  __syncthreads();

  // LN2 + mask; keep normalized f32 in regs; stash bf16 into As for selfb GEMM
  float xn[16];
  const int lrow = t >> 3, loct = t & 7;
  {
    float x[16], sm = 0.f;
#pragma unroll
    for (int i = 0; i < 16; ++i) { x[i] = h2[lrow * HH + loct * 16 + i]; sm += x[i]; }
    sm += __shfl_xor(sm, 1, 64); sm += __shfl_xor(sm, 2, 64); sm += __shfl_xor(sm, 4, 64);
    const float mu = sm * (1.f / HH);
    float vv = 0.f;
#pragma unroll
    for (int i = 0; i < 16; ++i) { const float d = x[i] - mu; vv += d * d; }
    vv += __shfl_xor(vv, 1, 64); vv += __shfl_xor(vv, 2, 64); vv += __shfl_xor(vv, 4, 64);
    const float rs = rsqrtf(vv * (1.f / HH) + LEPS);
    const float m1v = mask[row0 + lrow];
#pragma unroll
    for (int i = 0; i < 16; ++i) {
      const int col = loct * 16 + i;
      xn[i] = (g2[col] * (x[i] - mu) * rs + bt2[col]) * m1v;
      const ushort_t ov = f2us(xn[i]);
      hV_out[(size_t)(row0 + lrow) * HH + col] = ov;
      sw_store1(As, lrow, 256, col, ov);
    }
  }

  // ---- fused: selfb_out = hV_out @ Wn1self + bn1 (next layer) ----
  if (Wn1f != nullptr) {
    __syncthreads();  // As fully written
    f32x4 sa[2][2];
#pragma unroll
    for (int ni = 0; ni < 2; ++ni) {
      const float bv = bn1[wid * 32 + ni * 16 + (lane & 15)];
#pragma unroll
      for (int mi = 0; mi < 2; ++mi) sa[mi][ni] = {bv, bv, bv, bv};
    }
#pragma unroll
    for (int kb = 0; kb < 4; ++kb) {
      short8 A[2], Bf[2];
#pragma unroll
      for (int mi = 0; mi < 2; ++mi)
        A[mi] = sw_load8(As, mi * 16 + (lane & 15), 256, kb * 64 + (lane >> 4) * 16);
#pragma unroll
      for (int ni = 0; ni < 2; ++ni)
        Bf[ni] = *(const short8*)&Wn1f[(((size_t)kb * 8 + wid * 2 + ni) * 64 + lane) * 8];
#pragma unroll
      for (int mi = 0; mi < 2; ++mi)
#pragma unroll
        for (int ni = 0; ni < 2; ++ni)
          sa[mi][ni] = __builtin_amdgcn_mfma_f32_16x16x32_bf16(A[mi], Bf[ni], sa[mi][ni], 0, 0, 0);
    }
#pragma unroll
    for (int mi = 0; mi < 2; ++mi)
#pragma unroll
      for (int ni = 0; ni < 2; ++ni)
#pragma unroll
        for (int q = 0; q < 4; ++q) {
          const int row = mi * 16 + (lane >> 4) * 4 + q;
          const int col = wid * 32 + ni * 16 + (lane & 15);
          selfb_out[(size_t)(row0 + row) * HH + col] = f2us(sa[mi][ni][q]);
        }
  }

  // ---- fused (final layer): logits + log_softmax from pre-rounding f32 ----
  if (lout != nullptr) {
    __syncthreads();                // all h2 reads done; Us reusable
    float* wlds = (float*)Us;       // [128][NV] f32 = 10.5KB
    for (int i = t; i < HH * NV; i += 256) wlds[i] = Wout[i];
    __syncthreads();

    float p[NV];
#pragma unroll
    for (int v = 0; v < NV; ++v) p[v] = 0.f;
#pragma unroll
    for (int i = 0; i < 16; ++i) {
      const float xv = xn[i];
      const float* wr = wlds + (loct * 16 + i) * NV;
#pragma unroll
      for (int v = 0; v < NV; ++v) p[v] += xv * wr[v];
    }
#pragma unroll
    for (int v = 0; v < NV; ++v) {
      p[v] += __shfl_xor(p[v], 1, 64);
      p[v] += __shfl_xor(p[v], 2, 64);
      p[v] += __shfl_xor(p[v], 4, 64);
    }
    if (loct == 0) {
      float mx = -1e30f;
#pragma unroll
      for (int v = 0; v < NV; ++v) { p[v] += bout[v]; mx = fmaxf(mx, p[v]); }
      float s = 0.f;
#pragma unroll
      for (int v = 0; v < NV; ++v) s += expf(p[v] - mx);
      const float lse = mx + logf(s);
      float* o = lout + (size_t)(row0 + lrow) * NV;
#pragma unroll
      for (int v = 0; v < NV; ++v) o[v] = p[v] - lse;
    }
  }
}

// ---------------- launcher ----------------
extern "C" void kernel_launch(void* const* d_in, const int* in_sizes, int n_in,
                              void* d_out, int out_size, void* d_ws, size_t ws_size,
                              hipStream_t stream)
{
  const int* S = (const int*)d_in[0];
  const float* V = (const float*)d_in[1];
  const float* E = (const float*)d_in[2];
  const int* E_idx = (const int*)d_in[3];
  const float* mask = (const float*)d_in[4];
  const float* Wv = (const float*)d_in[5];
  const float* bv = (const float*)d_in[6];
  const float* We = (const float*)d_in[7];
  const float* be = (const float*)d_in[8];
  const float* Wse = (const float*)d_in[9];
  const float* Wout = (const float*)d_in[10];
  const float* bout = (const float*)d_in[11];
  const float* eW[14];
  const float* dW[14];
  for (int i = 0; i < 14; ++i) eW[i] = (const float*)d_in[12 + i];
  for (int i = 0; i < 14; ++i) dW[i] = (const float*)d_in[26 + i];

  // ws layout (bytes):
  //   hE    bf16 : 62,914,560 @ 0
  //   hVa16 bf16 :  2,097,152 @ 62,914,560
  //   hVb16 bf16 :  2,097,152 @ 65,011,712
  //   h1    bf16 :  2,097,152 @ 67,108,864
  //   hS    bf16 :  2,097,152 @ 69,206,016
  //   WP    bf16 :  2,719,744 @ 71,303,168
  //   selfb bf16 :  2,097,152 @ 74,022,912
  //   zbuf       :      1,024 @ 76,120,064   (end 76,121,088)
  char* w = (char*)d_ws;
  ushort_t* hE = (ushort_t*)w;
  ushort_t* hVa = (ushort_t*)(w + 62914560u);
  ushort_t* hVb = (ushort_t*)(w + 65011712u);
  ushort_t* h1 = (ushort_t*)(w + 67108864u);
  ushort_t* hS = (ushort_t*)(w + 69206016u);
  ushort_t* WP = (ushort_t*)(w + 71303168u);
  ushort_t* selfb = (ushort_t*)(w + 74022912u);
  ushort_t* zbuf = (ushort_t*)(w + 76120064u);

  const int R = 8 * NN;  // 8192

  // ---- build merged prep table (W1 split into self/rest; 38 tensors) ----
  PrepTab tab;
  int ti = 0, blk = 0;
  auto addT = [&](const float* src, unsigned dstOff, int K, int nshift) {
    tab.src[ti] = src; tab.dstOff[ti] = dstOff;
    tab.blk0[ti] = blk; tab.nshift[ti] = nshift;
    blk += (K << nshift) >> 8;
    ++ti;
  };
  for (int l = 0; l < 3; ++l) {
    const unsigned base = l * 212992u;
    addT(eW[0] + l * 384 * 128, base + 0, 128, 7);             // W1 self rows
    addT(eW[0] + l * 384 * 128 + 16384, base + 16384, 256, 7); // W1 rest rows
    addT(eW[2] + l * 128 * 128, base + 49152,  128, 7);
    addT(eW[4] + l * 128 * 128, base + 65536,  128, 7);
    addT(eW[6] + l * 128 * 512, base + 81920,  128, 9);
    addT(eW[8] + l * 512 * 128, base + 147456, 512, 7);
  }
  for (int l = 0; l < 3; ++l) {
    const unsigned base = 638976u + l * 229376u;
    addT(dW[0] + l * 512 * 128, base + 0, 128, 7);             // W1 self
    addT(dW[0] + l * 512 * 128 + 16384, base + 16384, 384, 7); // W1 rest
    addT(dW[2] + l * 128 * 128, base + 65536,  128, 7);
    addT(dW[4] + l * 128 * 128, base + 81920,  128, 7);
    addT(dW[6] + l * 128 * 512, base + 98304,  128, 9);
    addT(dW[8] + l * 512 * 128, base + 163840, 512, 7);
  }
  addT(We, 1327104u, 128, 7);
  addT(Wv, 1343488u, 128, 7);
  for (int i = ti; i < 40; ++i) { tab.src[i] = nullptr; tab.dstOff[i] = 0; tab.blk0[i] = 0x7FFFFFFF; tab.nshift[i] = 7; }
  k_prep_all<<<blk, 256, 0, stream>>>(tab, WP, (float*)zbuf);

  // ---- embeddings ----
  k_gemm64<<<R / 64, 256, 0, stream>>>(V, WP + 1343488, bv, hVa);        // h_V (bf16)
  k_hs<<<R * 32 / 256, 256, 0, stream>>>(S, Wse, hS);                     // h_S
  k_gemm64<<<R * KNBR / 64, 256, 0, stream>>>(E, WP + 1327104, be, hE);  // h_E

  // initial selfb (enc l=0) from hVa
  k_gemm64b<<<R / 64, 256, 0, stream>>>(hVa, WP, eW[1], selfb);

  // encoder (in-place on hVa); each k_ff produces selfb for the NEXT layer
  for (int l = 0; l < 3; ++l) {
    const ushort_t* base = WP + l * 212992;
    k_msg<0><<<2048, 256, 0, stream>>>(hVa, hVa, hS, hE,
        base + 16384, base + 49152, base + 65536, selfb, zbuf,
        eW[3] + l * 128, eW[5] + l * 128,
        eW[10] + l * 128, eW[11] + l * 128, E_idx, mask, h1);
    const ushort_t* nw1 = (l < 2) ? (WP + (l + 1) * 212992) : (WP + 638976);
    const float* nb1 = (l < 2) ? (eW[1] + (l + 1) * 128) : dW[1];
    k_ff<<<256, 256, 0, stream>>>(h1, base + 81920, base + 147456,
        eW[7] + l * 512, eW[9] + l * 128, eW[12] + l * 128, eW[13] + l * 128,
        mask, hVa, nw1, nb1, selfb, nullptr, nullptr, nullptr);
  }
  // decoder: hV_enc = hVa (preserved); state rotates into hVb
  for (int l = 0; l < 3; ++l) {
    const ushort_t* base = WP + 638976 + l * 229376;
    const ushort_t* hin = (l == 0) ? hVa : hVb;
    k_msg<1><<<2048, 256, 0, stream>>>(hin, hVa, hS, hE,
        base + 16384, base + 65536, base + 81920, selfb, zbuf,
        dW[3] + l * 128, dW[5] + l * 128,
        dW[10] + l * 128, dW[11] + l * 128, E_idx, mask, h1);
    const ushort_t* nw1 = (l < 2) ? (WP + 638976 + (l + 1) * 229376) : nullptr;
    const float* nb1 = (l < 2) ? (dW[1] + (l + 1) * 128) : nullptr;
    const float* wo = (l == 2) ? Wout : nullptr;
    const float* bo = (l == 2) ? bout : nullptr;
    float* lo = (l == 2) ? (float*)d_out : nullptr;
    k_ff<<<256, 256, 0, stream>>>(h1, base + 98304, base + 163840,
        dW[7] + l * 512, dW[9] + l * 128, dW[12] + l * 128, dW[13] + l * 128,
        mask, hVb, nw1, nb1, selfb, wo, bo, lo);
  }

  (void)in_sizes; (void)n_in; (void)out_size; (void)ws_size;
}

// Round 18
// 481.240 us; speedup vs baseline: 1.0116x; 1.0116x over previous
//
#include <hip/hip_runtime.h>
#include <hip/hip_bf16.h>

#define HH 128
#define NN 1024
#define KNBR 30
#define NV 21
#define LEPS 1e-5f

typedef unsigned short ushort_t;
typedef __attribute__((ext_vector_type(8))) short short8;
typedef __attribute__((ext_vector_type(4))) short shortv4;
typedef __attribute__((ext_vector_type(4))) float f32x4;

__device__ __forceinline__ ushort_t f2us(float f) {
  __hip_bfloat16 h = __float2bfloat16(f);
  return __builtin_bit_cast(unsigned short, h);
}
__device__ __forceinline__ float us2f(ushort_t u) {
  __hip_bfloat16 h = __builtin_bit_cast(__hip_bfloat16, u);
  return __bfloat162float(h);
}

// async global->LDS 16B copy (lane l writes lds + l*16)
__device__ __forceinline__ void gl_lds16(const ushort_t* g, ushort_t* l) {
  __builtin_amdgcn_global_load_lds(
      (const __attribute__((address_space(1))) void*)g,
      (__attribute__((address_space(3))) void*)l, 16, 0, 0);
}

// XOR-swizzled LDS helpers (row-major, rowB bytes/row, swizzle within 128B)
__device__ __forceinline__ void sw_store8(ushort_t* base, int row, int rowB, int colByte, short8 v) {
  int byte = row * rowB + colByte;
  byte ^= (row & 7) << 4;
  *(short8*)((char*)base + byte) = v;
}
__device__ __forceinline__ short8 sw_load8(const ushort_t* base, int row, int rowB, int colByte) {
  int byte = row * rowB + colByte;
  byte ^= (row & 7) << 4;
  return *(const short8*)((const char*)base + byte);
}
__device__ __forceinline__ void sw_store1(ushort_t* base, int row, int rowB, int col, ushort_t v) {
  int byte = row * rowB + col * 2;
  byte ^= (row & 7) << 4;
  *(ushort_t*)((char*)base + byte) = v;
}

// ---------------- merged weight prep: up to 40 tensors in one launch ----------------
// frag idx: ((k>>5)*NT + (c>>4))*512 + (((k&31)>>3)*16 + (c&15))*8 + (k&7)
struct PrepTab {
  const float* src[40];
  unsigned dstOff[40];
  int blk0[40];     // starting block of each tensor (each block = 256 elems)
  int nshift[40];
};

__global__ __launch_bounds__(256) void k_prep_all(PrepTab tab, ushort_t* __restrict__ dst,
                                                  float* __restrict__ zbuf) {
  const int bid = blockIdx.x;
  if (bid == 0) zbuf[threadIdx.x] = 0.f;  // 1KB zero region for gather zero-fill
  int ti = 0;
#pragma unroll 1
  for (int i = 1; i < 40; ++i)
    if (bid >= tab.blk0[i]) ti = i;
  const int nshift = tab.nshift[ti];
  const int e = (bid - tab.blk0[ti]) * 256 + threadIdx.x;
  const int k = e >> nshift;
  const int c = e & ((1 << nshift) - 1);
  const int NT = 1 << (nshift - 4);
  const int idx = ((k >> 5) * NT + (c >> 4)) * 512 + (((k & 31) >> 3) * 16 + (c & 15)) * 8 + (k & 7);
  dst[tab.dstOff[ti] + idx] = f2us(tab.src[ti][e]);
}

// ---------------- 64x128x128 MFMA GEMM over row tiles (f32 A), bf16 out ----------------
// Optional fused second GEMM: selfb_out = C_bf16 @ Wn1f + bn1 (C tile already in LDS).
__global__ __launch_bounds__(256) void k_gemm64(
    const float* __restrict__ A, const ushort_t* __restrict__ Wf,
    const float* __restrict__ bias, ushort_t* __restrict__ out,
    const ushort_t* __restrict__ Wn1f, const float* __restrict__ bn1,
    ushort_t* __restrict__ selfb_out)
{
  const int t = threadIdx.x, wid = t >> 6, lane = t & 63;
  const int wm = wid >> 1, wn = wid & 1;
  const size_t row0 = (size_t)blockIdx.x * 64;
  __shared__ alignas(16) ushort_t Xs[64 * 128];  // 16KB, rowB=256

  {
    const int row = t >> 2, q = t & 3;
    const float4* p = (const float4*)(A + (row0 + row) * HH + q * 32);
#pragma unroll
    for (int i = 0; i < 4; ++i) {
      short8 wv;
#pragma unroll
      for (int jj = 0; jj < 2; ++jj) {
        const float4 x = p[i * 2 + jj];
        wv[jj * 4 + 0] = (short)f2us(x.x);
        wv[jj * 4 + 1] = (short)f2us(x.y);
        wv[jj * 4 + 2] = (short)f2us(x.z);
        wv[jj * 4 + 3] = (short)f2us(x.w);
      }
      sw_store8(Xs, row, 256, q * 64 + i * 16, wv);
    }
  }
  __syncthreads();

  f32x4 acc[2][4];
#pragma unroll
  for (int ni = 0; ni < 4; ++ni) {
    const float bv = bias[wn * 64 + ni * 16 + (lane & 15)];
#pragma unroll
    for (int mi = 0; mi < 2; ++mi) acc[mi][ni] = {bv, bv, bv, bv};
  }
#pragma unroll
  for (int kb = 0; kb < 4; ++kb) {
    short8 Af[2], Bf[4];
#pragma unroll
    for (int mi = 0; mi < 2; ++mi)
      Af[mi] = sw_load8(Xs, wm * 32 + mi * 16 + (lane & 15), 256, kb * 64 + (lane >> 4) * 16);
#pragma unroll
    for (int ni = 0; ni < 4; ++ni)
      Bf[ni] = *(const short8*)&Wf[(((size_t)kb * 8 + wn * 4 + ni) * 64 + lane) * 8];
#pragma unroll
    for (int mi = 0; mi < 2; ++mi)
#pragma unroll
      for (int ni = 0; ni < 4; ++ni)
        acc[mi][ni] = __builtin_amdgcn_mfma_f32_16x16x32_bf16(Af[mi], Bf[ni], acc[mi][ni], 0, 0, 0);
  }

  __syncthreads();
#pragma unroll
  for (int mi = 0; mi < 2; ++mi)
#pragma unroll
    for (int ni = 0; ni < 4; ++ni)
#pragma unroll
      for (int q = 0; q < 4; ++q) {
        const int row = wm * 32 + mi * 16 + (lane >> 4) * 4 + q;
        const int col = wn * 64 + ni * 16 + (lane & 15);
        sw_store1(Xs, row, 256, col, f2us(acc[mi][ni][q]));
      }
  __syncthreads();
  {
    const int row = t >> 2, q = t & 3;
    ushort_t* o = out + (row0 + row) * HH + q * 32;
#pragma unroll
    for (int i = 0; i < 4; ++i)
      *(short8*)(o + i * 8) = sw_load8(Xs, row, 256, q * 64 + i * 16);
  }

  // ---- fused: selfb_out = C @ Wn1f + bn1 (C tile = Xs, bf16 swizzled) ----
  if (selfb_out != nullptr) {
#pragma unroll
    for (int ni = 0; ni < 4; ++ni) {
      const float bv = bn1[wn * 64 + ni * 16 + (lane & 15)];
#pragma unroll
      for (int mi = 0; mi < 2; ++mi) acc[mi][ni] = {bv, bv, bv, bv};
    }
#pragma unroll
    for (int kb = 0; kb < 4; ++kb) {
      short8 Af[2], Bf[4];
#pragma unroll
      for (int mi = 0; mi < 2; ++mi)
        Af[mi] = sw_load8(Xs, wm * 32 + mi * 16 + (lane & 15), 256, kb * 64 + (lane >> 4) * 16);
#pragma unroll
      for (int ni = 0; ni < 4; ++ni)
        Bf[ni] = *(const short8*)&Wn1f[(((size_t)kb * 8 + wn * 4 + ni) * 64 + lane) * 8];
#pragma unroll
      for (int mi = 0; mi < 2; ++mi)
#pragma unroll
        for (int ni = 0; ni < 4; ++ni)
          acc[mi][ni] = __builtin_amdgcn_mfma_f32_16x16x32_bf16(Af[mi], Bf[ni], acc[mi][ni], 0, 0, 0);
    }
#pragma unroll
    for (int mi = 0; mi < 2; ++mi)
#pragma unroll
      for (int ni = 0; ni < 4; ++ni)
#pragma unroll
        for (int q = 0; q < 4; ++q) {
          const int row = wm * 32 + mi * 16 + (lane >> 4) * 4 + q;
          const int col = wn * 64 + ni * 16 + (lane & 15);
          selfb_out[(row0 + row) * HH + col] = f2us(acc[mi][ni][q]);
        }
  }
}

// ---------------- h_S = Ws_emb[S] (bf16), vectorized gather ----------------
__global__ __launch_bounds__(256) void k_hs(
    const int* __restrict__ S, const float* __restrict__ Wse, ushort_t* __restrict__ hS)
{
  const int e = blockIdx.x * 256 + threadIdx.x;
  const int r = e >> 5, cq = e & 31;
  const float4 x = *(const float4*)(Wse + (size_t)S[r] * HH + cq * 4);
  shortv4 v;
  v[0] = (short)f2us(x.x); v[1] = (short)f2us(x.y);
  v[2] = (short)f2us(x.z); v[3] = (short)f2us(x.w);
  *(shortv4*)(hS + (size_t)r * HH + cq * 4) = v;
}

// ---------------- MFMA message kernel: global_load_lds staging ----------------
// Gather pointers compressed to u32 element-offsets from the ws base (all
// gather targets live in d_ws) -> ~12 fewer VGPRs; saddr+voffset load form.
template <int DEC>
__global__ __launch_bounds__(256) void k_msg(
    const ushort_t* __restrict__ wsbase,
    const ushort_t* __restrict__ hV_in, const ushort_t* __restrict__ hV_enc,
    const ushort_t* __restrict__ hS, const ushort_t* __restrict__ hE,
    const ushort_t* __restrict__ W1f, const ushort_t* __restrict__ W2f,
    const ushort_t* __restrict__ W3f, const ushort_t* __restrict__ selfb,
    const ushort_t* __restrict__ zbuf,
    const float* __restrict__ b2, const float* __restrict__ b3,
    const float* __restrict__ g1, const float* __restrict__ bt1,
    const int* __restrict__ E_idx, const float* __restrict__ mask,
    ushort_t* __restrict__ h1out)
{
  constexpr int INFR = DEC ? 3 * HH : 2 * HH;   // X width excluding self block
  constexpr int SLABS = INFR / 64;              // 6 (dec) / 4 (enc)
  const int t = threadIdx.x;
  const int wid = t >> 6, lane = t & 63;
  const int wm = wid >> 1, wn = wid & 1;
  const int node0 = blockIdx.x * 4;
  const int bb = node0 >> 10;
  const int np0 = node0 & (NN - 1);

  __shared__ alignas(16) ushort_t U[128 * 128];  // 32KB union: {Xa|Xb} | Ys | dhs
  __shared__ int s_nb[128];
  __shared__ float s_watt[128];
  __shared__ signed char s_ar[128];
  __shared__ float sself[4][HH];                 // 2KB: per-node self term (f32)
  ushort_t* Xa = U;
  ushort_t* Xb = U + 128 * 64;
  ushort_t* Ys = U;
  float* dhs = (float*)U;

  if (t < 128) {
    const int g = t >> 5, e = t & 31;
    const int r = node0 + g;
    int nb = 0, arI = 0;
    float watt = 0.f;
    if (e < KNBR) {
      nb = E_idx[(size_t)r * KNBR + e];
      if (DEC) {
        arI = (nb < np0 + g) ? 1 : 0;
        watt = 1.f;
      } else {
        watt = mask[r] * mask[bb * NN + nb];
      }
    }
    s_nb[t] = nb; s_watt[t] = watt; s_ar[t] = (signed char)arI;
  }
  // stage selfb for the block's 4 nodes (512 elems, 2 per thread)
  {
    const int i0 = t, i1 = t + 256;
    sself[i0 >> 7][i0 & 127] = us2f(selfb[(size_t)(node0 + (i0 >> 7)) * HH + (i0 & 127)]);
    sself[i1 >> 7][i1 & 127] = us2f(selfb[(size_t)(node0 + (i1 >> 7)) * HH + (i1 & 127)]);
  }
  __syncthreads();

  // ---- per-j pre-swizzled gather offsets (u32 elements from wsbase) ----
  const unsigned elemOff = (((lane & 7) ^ (lane >> 3)) << 3);
  const unsigned offHE = (unsigned)(hE - wsbase);
  const unsigned offHS = (unsigned)(hS - wsbase);
  const unsigned offVI = (unsigned)(hV_in - wsbase);
  const unsigned offVE = (unsigned)(hV_enc - wsbase);
  const unsigned offZ = (unsigned)(zbuf - wsbase);
  unsigned oj0[4], oj1[4], oj2[4];
#pragma unroll
  for (int j = 0; j < 4; ++j) {
    const int se = j * 8 + (lane >> 3);
    const bool valid = (se < KNBR);
    const int nb = s_nb[wid * 32 + se];
    const bool ar = (bool)s_ar[wid * 32 + se];
    oj0[j] = valid ? (offHE + (unsigned)(((node0 + wid) * KNBR + se) * HH) + elemOff) : offZ;
    if (DEC) {
      oj1[j] = (valid && ar) ? (offHS + (unsigned)((bb * NN + nb) * HH) + elemOff) : offZ;
      oj2[j] = valid ? ((ar ? offVI : offVE) + (unsigned)((bb * NN + nb) * HH) + elemOff) : offZ;
    } else {
      oj1[j] = valid ? (offVI + (unsigned)((bb * NN + nb) * HH) + elemOff) : offZ;
      oj2[j] = offZ;
    }
  }

  auto stage_async = [&](int s, ushort_t* buf) {
#pragma unroll
    for (int j = 0; j < 4; ++j) {
      const unsigned off = (s < 2) ? oj0[j] : ((!DEC || s < 4) ? oj1[j] : oj2[j]);
      gl_lds16(wsbase + off + (s & 1) * 64, buf + wid * 2048 + j * 512);
    }
  };

  // acc init from self term (same value for all 4 q-rows of a node)
  f32x4 acc[4][4];
#pragma unroll
  for (int mi = 0; mi < 4; ++mi) {
    const int g = wm * 2 + (mi >> 1);
#pragma unroll
    for (int ni = 0; ni < 4; ++ni) {
      const float v = sself[g][wn * 64 + ni * 16 + (lane & 15)];
      acc[mi][ni] = {v, v, v, v};
    }
  }

  // ---- GEMM1 (K = INFR): async double-buffered slabs, one barrier per slab ----
  stage_async(0, Xa);
  __syncthreads();  // drains vmcnt -> Xa ready

  for (int s = 0; s < SLABS; ++s) {
    ushort_t* cur = (s & 1) ? Xb : Xa;
    ushort_t* nxt = (s & 1) ? Xa : Xb;
    if (s + 1 < SLABS) stage_async(s + 1, nxt);  // async, lands before next barrier
#pragma unroll
    for (int kb = 0; kb < 2; ++kb) {
      const int kbg = s * 2 + kb;
      short8 A[4], Bf[4];
#pragma unroll
      for (int mi = 0; mi < 4; ++mi)
        A[mi] = sw_load8(cur, wm * 64 + mi * 16 + (lane & 15), 128, kb * 64 + (lane >> 4) * 16);
#pragma unroll
      for (int ni = 0; ni < 4; ++ni)
        Bf[ni] = *(const short8*)&W1f[(((size_t)kbg * 8 + wn * 4 + ni) * 64 + lane) * 8];
#pragma unroll
      for (int mi = 0; mi < 4; ++mi)
#pragma unroll
        for (int ni = 0; ni < 4; ++ni)
          acc[mi][ni] = __builtin_amdgcn_mfma_f32_16x16x32_bf16(A[mi], Bf[ni], acc[mi][ni], 0, 0, 0);
    }
    __syncthreads();
  }

  // write Y1 = relu(.) into union (X buffers dead after final barrier)
#pragma unroll
  for (int mi = 0; mi < 4; ++mi)
#pragma unroll
    for (int ni = 0; ni < 4; ++ni)
#pragma unroll
      for (int q = 0; q < 4; ++q) {
        const int row = wm * 64 + mi * 16 + (lane >> 4) * 4 + q;
        const int col = wn * 64 + ni * 16 + (lane & 15);
        sw_store1(Ys, row, 256, col, f2us(fmaxf(acc[mi][ni][q], 0.f)));
      }
  __syncthreads();

  // ---- GEMM2 ----
#pragma unroll
  for (int ni = 0; ni < 4; ++ni) {
    const float bv = b2[wn * 64 + ni * 16 + (lane & 15)];
#pragma unroll
    for (int mi = 0; mi < 4; ++mi) acc[mi][ni] = {bv, bv, bv, bv};
  }
#pragma unroll
  for (int kb = 0; kb < 4; ++kb) {
    short8 A[4], Bf[4];
#pragma unroll
    for (int mi = 0; mi < 4; ++mi)
      A[mi] = sw_load8(Ys, wm * 64 + mi * 16 + (lane & 15), 256, kb * 64 + (lane >> 4) * 16);
#pragma unroll
    for (int ni = 0; ni < 4; ++ni)
      Bf[ni] = *(const short8*)&W2f[(((size_t)kb * 8 + wn * 4 + ni) * 64 + lane) * 8];
#pragma unroll
    for (int mi = 0; mi < 4; ++mi)
#pragma unroll
      for (int ni = 0; ni < 4; ++ni)
        acc[mi][ni] = __builtin_amdgcn_mfma_f32_16x16x32_bf16(A[mi], Bf[ni], acc[mi][ni], 0, 0, 0);
  }
  __syncthreads();
#pragma unroll
  for (int mi = 0; mi < 4; ++mi)
#pragma unroll
    for (int ni = 0; ni < 4; ++ni)
#pragma unroll
      for (int q = 0; q < 4; ++q) {
        const int row = wm * 64 + mi * 16 + (lane >> 4) * 4 + q;
        const int col = wn * 64 + ni * 16 + (lane & 15);
        sw_store1(Ys, row, 256, col, f2us(fmaxf(acc[mi][ni][q], 0.f)));
      }
  __syncthreads();

  // ---- GEMM3 ----
#pragma unroll
  for (int ni = 0; ni < 4; ++ni) {
    const float bv = b3[wn * 64 + ni * 16 + (lane & 15)];
#pragma unroll
    for (int mi = 0; mi < 4; ++mi) acc[mi][ni] = {bv, bv, bv, bv};
  }
#pragma unroll
  for (int kb = 0; kb < 4; ++kb) {
    short8 A[4], Bf[4];
#pragma unroll
    for (int mi = 0; mi < 4; ++mi)
      A[mi] = sw_load8(Ys, wm * 64 + mi * 16 + (lane & 15), 256, kb * 64 + (lane >> 4) * 16);
#pragma unroll
    for (int ni = 0; ni < 4; ++ni)
      Bf[ni] = *(const short8*)&W3f[(((size_t)kb * 8 + wn * 4 + ni) * 64 + lane) * 8];
#pragma unroll
    for (int mi = 0; mi < 4; ++mi)
#pragma unroll
      for (int ni = 0; ni < 4; ++ni)
        acc[mi][ni] = __builtin_amdgcn_mfma_f32_16x16x32_bf16(A[mi], Bf[ni], acc[mi][ni], 0, 0, 0);
  }
  __syncthreads();  // Ys dead; dhs overlay becomes safe

  // ---- masked sum over edge rows -> dh ----
  float wrow[4][4];
#pragma unroll
  for (int mi = 0; mi < 4; ++mi)
#pragma unroll
    for (int q = 0; q < 4; ++q)
      wrow[mi][q] = s_watt[wm * 64 + mi * 16 + (lane >> 4) * 4 + q];
#pragma unroll
  for (int ni = 0; ni < 4; ++ni) {
    float p0 = 0.f, p1 = 0.f;
#pragma unroll
    for (int q = 0; q < 4; ++q) {
      p0 += wrow[0][q] * acc[0][ni][q] + wrow[1][q] * acc[1][ni][q];
      p1 += wrow[2][q] * acc[2][ni][q] + wrow[3][q] * acc[3][ni][q];
    }
    p0 += __shfl_xor(p0, 16, 64); p0 += __shfl_xor(p0, 32, 64);
    p1 += __shfl_xor(p1, 16, 64); p1 += __shfl_xor(p1, 32, 64);
    if (lane < 16) {
      dhs[(wm * 2 + 0) * HH + wn * 64 + ni * 16 + lane] = p0;
      dhs[(wm * 2 + 1) * HH + wn * 64 + ni * 16 + lane] = p1;
    }
  }
  __syncthreads();

  // ---- LN1: wave wid handles node wid ----
  {
    const int r = node0 + wid;
    const float x0 = us2f(hV_in[(size_t)r * HH + lane]) + dhs[wid * HH + lane] * (1.f / 30.f);
    const float x1 = us2f(hV_in[(size_t)r * HH + lane + 64]) + dhs[wid * HH + lane + 64] * (1.f / 30.f);
    float sm2 = x0 + x1;
#pragma unroll
    for (int m = 32; m >= 1; m >>= 1) sm2 += __shfl_xor(sm2, m, 64);
    const float mu = sm2 * (1.f / HH);
    const float d0 = x0 - mu, d1 = x1 - mu;
    float vv = d0 * d0 + d1 * d1;
#pragma unroll
    for (int m = 32; m >= 1; m >>= 1) vv += __shfl_xor(vv, m, 64);
    const float rs = rsqrtf(vv * (1.f / HH) + LEPS);
    h1out[(size_t)r * HH + lane] = f2us(g1[lane] * d0 * rs + bt1[lane]);
    h1out[(size_t)r * HH + lane + 64] = f2us(g1[lane + 64] * d1 * rs + bt1[lane + 64]);
  }
}

// ---------------- FF kernel: 32 rows/block; bf16 hV out; fused next-layer selfb;
// optional fused logits + log_softmax (final layer) ----------------
__global__ __launch_bounds__(256) void k_ff(
    const ushort_t* __restrict__ h1, const ushort_t* __restrict__ Winf,
    const ushort_t* __restrict__ Wfff,
    const float* __restrict__ bin, const float* __restrict__ bff,
    const float* __restrict__ g2, const float* __restrict__ bt2,
    const float* __restrict__ mask, ushort_t* __restrict__ hV_out,
    const ushort_t* __restrict__ Wn1f, const float* __restrict__ bn1,
    ushort_t* __restrict__ selfb_out,
    const float* __restrict__ Wout, const float* __restrict__ bout,
    float* __restrict__ lout)
{
  const int t = threadIdx.x, wid = t >> 6, lane = t & 63;
  const int row0 = blockIdx.x * 32;
  __shared__ alignas(16) ushort_t As[32 * 128];
  __shared__ alignas(16) ushort_t Us[32 * 512];

  {
    const int row = t >> 3, oct = t & 7;
    const short8* p = (const short8*)(h1 + (size_t)(row0 + row) * HH + oct * 16);
    sw_store8(As, row, 256, oct * 32, p[0]);
    sw_store8(As, row, 256, oct * 32 + 16, p[1]);
  }
  __syncthreads();

  f32x4 ua[2][8];
#pragma unroll
  for (int ni = 0; ni < 8; ++ni) {
    const float bv = bin[wid * 128 + ni * 16 + (lane & 15)];
#pragma unroll
    for (int mi = 0; mi < 2; ++mi) ua[mi][ni] = {bv, bv, bv, bv};
  }
#pragma unroll
  for (int kb = 0; kb < 4; ++kb) {
    short8 A[2], Bf[8];
#pragma unroll
    for (int mi = 0; mi < 2; ++mi)
      A[mi] = sw_load8(As, mi * 16 + (lane & 15), 256, kb * 64 + (lane >> 4) * 16);
#pragma unroll
    for (int ni = 0; ni < 8; ++ni)
      Bf[ni] = *(const short8*)&Winf[(((size_t)kb * 32 + wid * 8 + ni) * 64 + lane) * 8];
#pragma unroll
    for (int mi = 0; mi < 2; ++mi)
#pragma unroll
      for (int ni = 0; ni < 8; ++ni)
        ua[mi][ni] = __builtin_amdgcn_mfma_f32_16x16x32_bf16(A[mi], Bf[ni], ua[mi][ni], 0, 0, 0);
  }
#pragma unroll
  for (int mi = 0; mi < 2; ++mi)
#pragma unroll
    for (int ni = 0; ni < 8; ++ni)
#pragma unroll
      for (int q = 0; q < 4; ++q) {
        const int row = mi * 16 + (lane >> 4) * 4 + q;
        const int col = wid * 128 + ni * 16 + (lane & 15);
        sw_store1(Us, row, 1024, col, f2us(fmaxf(ua[mi][ni][q], 0.f)));
      }
  __syncthreads();

  f32x4 fa[2][2];
#pragma unroll
  for (int ni = 0; ni < 2; ++ni) {
    const float bv = bff[wid * 32 + ni * 16 + (lane & 15)];
#pragma unroll
    for (int mi = 0; mi < 2; ++mi) fa[mi][ni] = {bv, bv, bv, bv};
  }
#pragma unroll
  for (int kb = 0; kb < 16; ++kb) {
    short8 A[2], Bf[2];
#pragma unroll
    for (int mi = 0; mi < 2; ++mi)
      A[mi] = sw_load8(Us, mi * 16 + (lane & 15), 1024, kb * 64 + (lane >> 4) * 16);
#pragma unroll
    for (int ni = 0; ni < 2; ++ni)
      Bf[ni] = *(const short8*)&Wfff[(((size_t)kb * 8 + wid * 2 + ni) * 64 + lane) * 8];
#pragma unroll
    for (int mi = 0; mi < 2; ++mi)
#pragma unroll
      for (int ni = 0; ni < 2; ++ni)
        fa[mi][ni] = __builtin_amdgcn_mfma_f32_16x16x32_bf16(A[mi], Bf[ni], fa[mi][ni], 0, 0, 0);
  }
  __syncthreads();

  float* h2 = (float*)Us;
#pragma unroll
  for (int mi = 0; mi < 2; ++mi)
#pragma unroll
    for (int ni = 0; ni < 2; ++ni)
#pragma unroll
      for (int q = 0; q < 4; ++q) {
        const int row = mi * 16 + (lane >> 4) * 4 + q;
        const int col = wid * 32 + ni * 16 + (lane & 15);
        h2[row * HH + col] = us2f(h1[(size_t)(row0 + row) * HH + col]) + fa[mi][ni][q];
      }
  __syncthreads();

  // LN2 + mask; keep normalized f32 in regs; stash bf16 into As for selfb GEMM
  float xn[16];
  const int lrow = t >> 3, loct = t & 7;
  {
    float x[16], sm = 0.f;
#pragma unroll
    for (int i = 0; i < 16; ++i) { x[i] = h2[lrow * HH + loct * 16 + i]; sm += x[i]; }
    sm += __shfl_xor(sm, 1, 64); sm += __shfl_xor(sm, 2, 64); sm += __shfl_xor(sm, 4, 64);
    const float mu = sm * (1.f / HH);
    float vv = 0.f;
#pragma unroll
    for (int i = 0; i < 16; ++i) { const float d = x[i] - mu; vv += d * d; }
    vv += __shfl_xor(vv, 1, 64); vv += __shfl_xor(vv, 2, 64); vv += __shfl_xor(vv, 4, 64);
    const float rs = rsqrtf(vv * (1.f / HH) + LEPS);
    const float m1v = mask[row0 + lrow];
#pragma unroll
    for (int i = 0; i < 16; ++i) {
      const int col = loct * 16 + i;
      xn[i] = (g2[col] * (x[i] - mu) * rs + bt2[col]) * m1v;
      const ushort_t ov = f2us(xn[i]);
      hV_out[(size_t)(row0 + lrow) * HH + col] = ov;
      sw_store1(As, lrow, 256, col, ov);
    }
  }

  // ---- fused: selfb_out = hV_out @ Wn1self + bn1 (next layer) ----
  if (Wn1f != nullptr) {
    __syncthreads();  // As fully written
    f32x4 sa[2][2];
#pragma unroll
    for (int ni = 0; ni < 2; ++ni) {
      const float bv = bn1[wid * 32 + ni * 16 + (lane & 15)];
#pragma unroll
      for (int mi = 0; mi < 2; ++mi) sa[mi][ni] = {bv, bv, bv, bv};
    }
#pragma unroll
    for (int kb = 0; kb < 4; ++kb) {
      short8 A[2], Bf[2];
#pragma unroll
      for (int mi = 0; mi < 2; ++mi)
        A[mi] = sw_load8(As, mi * 16 + (lane & 15), 256, kb * 64 + (lane >> 4) * 16);
#pragma unroll
      for (int ni = 0; ni < 2; ++ni)
        Bf[ni] = *(const short8*)&Wn1f[(((size_t)kb * 8 + wid * 2 + ni) * 64 + lane) * 8];
#pragma unroll
      for (int mi = 0; mi < 2; ++mi)
#pragma unroll
        for (int ni = 0; ni < 2; ++ni)
          sa[mi][ni] = __builtin_amdgcn_mfma_f32_16x16x32_bf16(A[mi], Bf[ni], sa[mi][ni], 0, 0, 0);
    }
#pragma unroll
    for (int mi = 0; mi < 2; ++mi)
#pragma unroll
      for (int ni = 0; ni < 2; ++ni)
#pragma unroll
        for (int q = 0; q < 4; ++q) {
          const int row = mi * 16 + (lane >> 4) * 4 + q;
          const int col = wid * 32 + ni * 16 + (lane & 15);
          selfb_out[(size_t)(row0 + row) * HH + col] = f2us(sa[mi][ni][q]);
        }
  }

  // ---- fused (final layer): logits + log_softmax from pre-rounding f32 ----
  if (lout != nullptr) {
    __syncthreads();                // all h2 reads done; Us reusable
    float* wlds = (float*)Us;       // [128][NV] f32 = 10.5KB
    for (int i = t; i < HH * NV; i += 256) wlds[i] = Wout[i];
    __syncthreads();

    float p[NV];
#pragma unroll
    for (int v = 0; v < NV; ++v) p[v] = 0.f;
#pragma unroll
    for (int i = 0; i < 16; ++i) {
      const float xv = xn[i];
      const float* wr = wlds + (loct * 16 + i) * NV;
#pragma unroll
      for (int v = 0; v < NV; ++v) p[v] += xv * wr[v];
    }
#pragma unroll
    for (int v = 0; v < NV; ++v) {
      p[v] += __shfl_xor(p[v], 1, 64);
      p[v] += __shfl_xor(p[v], 2, 64);
      p[v] += __shfl_xor(p[v], 4, 64);
    }
    if (loct == 0) {
      float mx = -1e30f;
#pragma unroll
      for (int v = 0; v < NV; ++v) { p[v] += bout[v]; mx = fmaxf(mx, p[v]); }
      float s = 0.f;
#pragma unroll
      for (int v = 0; v < NV; ++v) s += expf(p[v] - mx);
      const float lse = mx + logf(s);
      float* o = lout + (size_t)(row0 + lrow) * NV;
#pragma unroll
      for (int v = 0; v < NV; ++v) o[v] = p[v] - lse;
    }
  }
}

// ---------------- launcher ----------------
extern "C" void kernel_launch(void* const* d_in, const int* in_sizes, int n_in,
                              void* d_out, int out_size, void* d_ws, size_t ws_size,
                              hipStream_t stream)
{
  const int* S = (const int*)d_in[0];
  const float* V = (const float*)d_in[1];
  const float* E = (const float*)d_in[2];
  const int* E_idx = (const int*)d_in[3];
  const float* mask = (const float*)d_in[4];
  const float* Wv = (const float*)d_in[5];
  const float* bv = (const float*)d_in[6];
  const float* We = (const float*)d_in[7];
  const float* be = (const float*)d_in[8];
  const float* Wse = (const float*)d_in[9];
  const float* Wout = (const float*)d_in[10];
  const float* bout = (const float*)d_in[11];
  const float* eW[14];
  const float* dW[14];
  for (int i = 0; i < 14; ++i) eW[i] = (const float*)d_in[12 + i];
  for (int i = 0; i < 14; ++i) dW[i] = (const float*)d_in[26 + i];

  // ws layout (bytes):
  //   hE    bf16 : 62,914,560 @ 0
  //   hVa16 bf16 :  2,097,152 @ 62,914,560
  //   hVb16 bf16 :  2,097,152 @ 65,011,712
  //   h1    bf16 :  2,097,152 @ 67,108,864
  //   hS    bf16 :  2,097,152 @ 69,206,016
  //   WP    bf16 :  2,719,744 @ 71,303,168
  //   selfb bf16 :  2,097,152 @ 74,022,912
  //   zbuf       :      1,024 @ 76,120,064   (end 76,121,088)
  char* w = (char*)d_ws;
  ushort_t* wsb = (ushort_t*)w;
  ushort_t* hE = (ushort_t*)w;
  ushort_t* hVa = (ushort_t*)(w + 62914560u);
  ushort_t* hVb = (ushort_t*)(w + 65011712u);
  ushort_t* h1 = (ushort_t*)(w + 67108864u);
  ushort_t* hS = (ushort_t*)(w + 69206016u);
  ushort_t* WP = (ushort_t*)(w + 71303168u);
  ushort_t* selfb = (ushort_t*)(w + 74022912u);
  ushort_t* zbuf = (ushort_t*)(w + 76120064u);

  const int R = 8 * NN;  // 8192

  // ---- build merged prep table (W1 split into self/rest; 38 tensors) ----
  PrepTab tab;
  int ti = 0, blk = 0;
  auto addT = [&](const float* src, unsigned dstOff, int K, int nshift) {
    tab.src[ti] = src; tab.dstOff[ti] = dstOff;
    tab.blk0[ti] = blk; tab.nshift[ti] = nshift;
    blk += (K << nshift) >> 8;
    ++ti;
  };
  for (int l = 0; l < 3; ++l) {
    const unsigned base = l * 212992u;
    addT(eW[0] + l * 384 * 128, base + 0, 128, 7);             // W1 self rows
    addT(eW[0] + l * 384 * 128 + 16384, base + 16384, 256, 7); // W1 rest rows
    addT(eW[2] + l * 128 * 128, base + 49152,  128, 7);
    addT(eW[4] + l * 128 * 128, base + 65536,  128, 7);
    addT(eW[6] + l * 128 * 512, base + 81920,  128, 9);
    addT(eW[8] + l * 512 * 128, base + 147456, 512, 7);
  }
  for (int l = 0; l < 3; ++l) {
    const unsigned base = 638976u + l * 229376u;
    addT(dW[0] + l * 512 * 128, base + 0, 128, 7);             // W1 self
    addT(dW[0] + l * 512 * 128 + 16384, base + 16384, 384, 7); // W1 rest
    addT(dW[2] + l * 128 * 128, base + 65536,  128, 7);
    addT(dW[4] + l * 128 * 128, base + 81920,  128, 7);
    addT(dW[6] + l * 128 * 512, base + 98304,  128, 9);
    addT(dW[8] + l * 512 * 128, base + 163840, 512, 7);
  }
  addT(We, 1327104u, 128, 7);
  addT(Wv, 1343488u, 128, 7);
  for (int i = ti; i < 40; ++i) { tab.src[i] = nullptr; tab.dstOff[i] = 0; tab.blk0[i] = 0x7FFFFFFF; tab.nshift[i] = 7; }
  k_prep_all<<<blk, 256, 0, stream>>>(tab, WP, (float*)zbuf);

  // ---- embeddings; h_V fuses the initial selfb (enc l=0) GEMM ----
  k_gemm64<<<R / 64, 256, 0, stream>>>(V, WP + 1343488, bv, hVa, WP, eW[1], selfb);
  k_hs<<<R * 32 / 256, 256, 0, stream>>>(S, Wse, hS);
  k_gemm64<<<R * KNBR / 64, 256, 0, stream>>>(E, WP + 1327104, be, hE,
                                              nullptr, nullptr, nullptr);

  // encoder (in-place on hVa); each k_ff produces selfb for the NEXT layer
  for (int l = 0; l < 3; ++l) {
    const ushort_t* base = WP + l * 212992;
    k_msg<0><<<2048, 256, 0, stream>>>(wsb, hVa, hVa, hS, hE,
        base + 16384, base + 49152, base + 65536, selfb, zbuf,
        eW[3] + l * 128, eW[5] + l * 128,
        eW[10] + l * 128, eW[11] + l * 128, E_idx, mask, h1);
    const ushort_t* nw1 = (l < 2) ? (WP + (l + 1) * 212992) : (WP + 638976);
    const float* nb1 = (l < 2) ? (eW[1] + (l + 1) * 128) : dW[1];
    k_ff<<<256, 256, 0, stream>>>(h1, base + 81920, base + 147456,
        eW[7] + l * 512, eW[9] + l * 128, eW[12] + l * 128, eW[13] + l * 128,
        mask, hVa, nw1, nb1, selfb, nullptr, nullptr, nullptr);
  }
  // decoder: hV_enc = hVa (preserved); state rotates into hVb
  for (int l = 0; l < 3; ++l) {
    const ushort_t* base = WP + 638976 + l * 229376;
    const ushort_t* hin = (l == 0) ? hVa : hVb;
    k_msg<1><<<2048, 256, 0, stream>>>(wsb, hin, hVa, hS, hE,
        base + 16384, base + 65536, base + 81920, selfb, zbuf,
        dW[3] + l * 128, dW[5] + l * 128,
        dW[10] + l * 128, dW[11] + l * 128, E_idx, mask, h1);
    const ushort_t* nw1 = (l < 2) ? (WP + 638976 + (l + 1) * 229376) : nullptr;
    const float* nb1 = (l < 2) ? (dW[1] + (l + 1) * 128) : nullptr;
    const float* wo = (l == 2) ? Wout : nullptr;
    const float* bo = (l == 2) ? bout : nullptr;
    float* lo = (l == 2) ? (float*)d_out : nullptr;
    k_ff<<<256, 256, 0, stream>>>(h1, base + 98304, base + 163840,
        dW[7] + l * 512, dW[9] + l * 128, dW[12] + l * 128, dW[13] + l * 128,
        mask, hVb, nw1, nb1, selfb, wo, bo, lo);
  }

  (void)in_sizes; (void)n_in; (void)out_size; (void)ws_size;
}